// Round 4
// baseline (304.137 us; speedup 1.0000x reference)
//
#include <hip/hip_runtime.h>

#define STRIDE 52
#define LDSN   (52 * 52)       // 2-cell guard ring around 48x48 interior
#define TINYF  1e-8f
#define NITER  50

// 5x5 symmetric conv over guarded buffer S (interior(r,c) at S[(r+2)*52 + c + 2],
// guard ring zeroed). Lane tile: interior rows R0..R0+2, cols C0..C0+11.
// wk[k*3+j] = weight for (|dy|=k, |dx|=j).
__device__ __forceinline__ void conv5(const float* __restrict__ S, int R0, int C0,
                                      const float* __restrict__ wk,
                                      float acc[3][12]) {
#pragma unroll
    for (int i = 0; i < 3; ++i)
#pragma unroll
        for (int c = 0; c < 12; ++c) acc[i][c] = 0.0f;

#pragma unroll
    for (int wr = 0; wr < 7; ++wr) {
        // window row = interior row R0-2+wr; reads cols C0-2 .. C0+13 (16B-aligned)
        const float4* rp = (const float4*)(S + (R0 + wr) * STRIDE + C0);
        float4 f0 = rp[0], f1 = rp[1], f2 = rp[2], f3 = rp[3];
        float win[16] = {f0.x, f0.y, f0.z, f0.w, f1.x, f1.y, f1.z, f1.w,
                         f2.x, f2.y, f2.z, f2.w, f3.x, f3.y, f3.z, f3.w};
        float s1[12], s2[12];
#pragma unroll
        for (int c = 0; c < 12; ++c) {
            s1[c] = win[c + 1] + win[c + 3];   // |dx| = 1 pair
            s2[c] = win[c] + win[c + 4];       // |dx| = 2 pair
        }
#pragma unroll
        for (int i = 0; i < 3; ++i) {
            const int dy = wr - 2 - i;
            if (dy < -2 || dy > 2) continue;
            const int k = dy < 0 ? -dy : dy;
#pragma unroll
            for (int c = 0; c < 12; ++c)
                acc[i][c] += wk[k * 3 + 0] * win[c + 2] +
                             wk[k * 3 + 1] * s1[c] +
                             wk[k * 3 + 2] * s2[c];
        }
    }
}

__device__ __forceinline__ float uni(float x) {
    return __uint_as_float(__builtin_amdgcn_readfirstlane(__float_as_uint(x)));
}

__global__ __launch_bounds__(64, 1)
void sinkhorn_wave(const float* __restrict__ hm_gt,
                   const float* __restrict__ hm_pred,
                   const int* __restrict__ tops,
                   float* __restrict__ out) {
    __shared__ __align__(16) float su_s[LDSN];
    __shared__ __align__(16) float sv_s[LDSN];

    const int t = threadIdx.x;
    const int blk = blockIdx.x;              // ((bi*8+rr)*5+cc)
    const int bi = blk / 40;
    const int rr = (blk / 5) % 8;
    const int cc = blk % 5;
    const int y0 = tops[(bi * 8 + rr) * 2 + 0];
    const int x0 = tops[(bi * 8 + rr) * 2 + 1];
    const float* srcA = hm_gt + (size_t)(bi * 5 + cc) * 25600;
    const float* srcB = hm_pred + (size_t)(bi * 5 + cc) * 25600;

    const int lr = t >> 2, lc = t & 3;       // 16 x 4 lane grid
    const int R0 = lr * 3, C0 = lc * 12;     // 3 x 12 pixel tile per lane

    // ---- zero both buffers (guard ring must be 0; interior overwritten) ----
#pragma unroll
    for (int k = t; k < LDSN / 4; k += 64) {
        ((float4*)su_s)[k] = make_float4(0.f, 0.f, 0.f, 0.f);
        ((float4*)sv_s)[k] = make_float4(0.f, 0.f, 0.f, 0.f);
    }

    // ---- load 3x12 tiles of both crops, reduce sums across the wave ----
    float va[36], vb[36];
    float sA = 0.f, sB = 0.f;
#pragma unroll
    for (int i = 0; i < 3; ++i) {
        const int g = (y0 + R0 + i) * 160 + x0 + C0;
#pragma unroll
        for (int q = 0; q < 12; ++q) {
            const float A = srcA[g + q];
            const float B = srcB[g + q];
            va[i * 12 + q] = A; vb[i * 12 + q] = B;
            sA += A; sB += B;
        }
    }
#pragma unroll
    for (int o = 1; o < 64; o <<= 1) {
        sA += __shfl_xor(sA, o, 64);
        sB += __shfl_xor(sB, o, 64);
    }
    const float rA = 1.0f / (sA + TINYF);
    const float rB = 1.0f / (sB + TINYF);
#pragma unroll
    for (int k = 0; k < 36; ++k) { va[k] *= rA; vb[k] *= rB; }

    // ---- u0 = 1/n interior ----
    const float u0 = 1.0f / 2304.0f;
#pragma unroll
    for (int i = 0; i < 3; ++i) {
        float2* wp = (float2*)(su_s + (R0 + i + 2) * STRIDE + C0 + 2);
#pragma unroll
        for (int j = 0; j < 6; ++j) wp[j] = make_float2(u0, u0);
    }
    __syncthreads();   // single-wave workgroup: ~free

    // ---- Gibbs weights by (|dy|,|dx|), wave-uniform -> SGPRs ----
    const float e10 = uni(expf(-1.0f / 0.1f));             // d = 1
    const float e2  = uni(expf(-sqrtf(2.0f) / 0.1f));      // d = sqrt(2)
    const float e20 = uni(expf(-2.0f / 0.1f));             // d = 2
    const float e5  = uni(expf(-sqrtf(5.0f) / 0.1f));      // d = sqrt(5)
    const float e8  = uni(expf(-sqrtf(8.0f) / 0.1f));      // d = 2*sqrt(2)
    const float wK[9] = {1.0f, e10, e20,
                         e10,  e2,  e5,
                         e20,  e5,  e8};

    float vv[36];

    // ---- Sinkhorn iterations ----
#pragma unroll 1
    for (int it = 0; it < NITER; ++it) {
        float acc[3][12];
        conv5(su_s, R0, C0, wK, acc);            // u @ K
#pragma unroll
        for (int i = 0; i < 3; ++i) {
#pragma unroll
            for (int c = 0; c < 12; ++c)
                vv[i * 12 + c] = vb[i * 12 + c] *
                    __builtin_amdgcn_rcpf(acc[i][c] + TINYF);
            float2* wp = (float2*)(sv_s + (R0 + i + 2) * STRIDE + C0 + 2);
#pragma unroll
            for (int j = 0; j < 6; ++j)
                wp[j] = make_float2(vv[i * 12 + 2 * j], vv[i * 12 + 2 * j + 1]);
        }
        __syncthreads();
        conv5(sv_s, R0, C0, wK, acc);            // v @ K^T (K symmetric)
#pragma unroll
        for (int i = 0; i < 3; ++i) {
            float uu[12];
#pragma unroll
            for (int c = 0; c < 12; ++c)
                uu[c] = va[i * 12 + c] *
                    __builtin_amdgcn_rcpf(acc[i][c] + TINYF);
            float2* wp = (float2*)(su_s + (R0 + i + 2) * STRIDE + C0 + 2);
#pragma unroll
            for (int j = 0; j < 6; ++j)
                wp[j] = make_float2(uu[2 * j], uu[2 * j + 1]);
        }
        __syncthreads();
    }

    // ---- loss: (u @ M) . v, M = K .* dist (center tap 0) ----
    const float s2f = sqrtf(2.0f), s5f = sqrtf(5.0f), s8f = sqrtf(8.0f);
    const float wM[9] = {0.0f,        e10 * 1.0f, e20 * 2.0f,
                         e10 * 1.0f,  e2 * s2f,   e5 * s5f,
                         e20 * 2.0f,  e5 * s5f,   e8 * s8f};
    float accM[3][12];
    conv5(su_s, R0, C0, wM, accM);
    float lsum = 0.f;
#pragma unroll
    for (int i = 0; i < 3; ++i)
#pragma unroll
        for (int c = 0; c < 12; ++c)
            lsum += accM[i][c] * vv[i * 12 + c];

#pragma unroll
    for (int o = 1; o < 64; o <<= 1) lsum += __shfl_xor(lsum, o, 64);
    if (t == 0) atomicAdd(out, lsum);
}

extern "C" void kernel_launch(void* const* d_in, const int* in_sizes, int n_in,
                              void* d_out, int out_size, void* d_ws, size_t ws_size,
                              hipStream_t stream) {
    (void)in_sizes; (void)n_in; (void)out_size; (void)d_ws; (void)ws_size;
    const float* hm_gt = (const float*)d_in[0];
    const float* hm_pred = (const float*)d_in[1];
    const int* tops = (const int*)d_in[2];
    float* out = (float*)d_out;

    hipMemsetAsync(out, 0, sizeof(float), stream);
    sinkhorn_wave<<<dim3(640), dim3(64), 0, stream>>>(hm_gt, hm_pred, tops, out);
}